// Round 7
// baseline (806.586 us; speedup 1.0000x reference)
//
#include <hip/hip_runtime.h>
#include <hip/hip_bf16.h>
#include <hip/hip_cooperative_groups.h>

// Problem constants
#define HH 256
#define WW 256
#define CCH 1024
#define PP 1024   // 32*32 patches per image

using f32x4 = __attribute__((ext_vector_type(4))) float;
using short8 = __attribute__((ext_vector_type(8))) short;

namespace cg = cooperative_groups;

// ===========================================================================
// Cooperative mega-kernel: 256 blocks x 512 threads (1 block/CU, 8 waves).
// Phases separated by grid.sync(); each phase is a port of the R5-proven
// bodies.  All cross-block writes are >=64B-granular (replay-safe).
// ===========================================================================
__global__ __launch_bounds__(512, 2) void fused_kernel(
        const float* __restrict__ x, const float* __restrict__ w,
        float* __restrict__ out,
        float* __restrict__ y, __hip_bfloat16* __restrict__ yT,
        __hip_bfloat16* __restrict__ wT, float* __restrict__ gate) {
    cg::grid_group grid = cg::this_grid();
    __shared__ __align__(16) float lds[32 * 33];

    const int bid  = blockIdx.x;    // 0..255
    const int t    = threadIdx.x;   // 0..511
    const int wid  = t >> 6;        // 0..7
    const int lane = t & 63;

    // ---- Phase 1: patch pool.  Wave w owns plane bid*8+w (all 32 patch-rows).
    // Wave reads full 256-col rows (f32x4/lane), shfl_xor(1) pair-reduce,
    // even lanes store 32 consecutive f32 (one 128B line per wave).
    {
        int plane = bid * 8 + wid;                // 0..2047 = b*1024+c
        const float* xp = x + (size_t)plane * (HH * WW) + lane * 4;
        float* yp = y + (size_t)plane * PP;
#pragma unroll 2
        for (int ph = 0; ph < 32; ++ph) {
            const float* slab = xp + (size_t)ph * 8 * WW;
            float acc = 0.f;
#pragma unroll
            for (int r = 0; r < 8; ++r) {
                f32x4 v = __builtin_nontemporal_load((const f32x4*)(slab + (size_t)r * WW));
                acc += v.x + v.y + v.z + v.w;
            }
            acc += __shfl_xor(acc, 1);
            if ((lane & 1) == 0)
                yp[ph * 32 + (lane >> 1)] = acc * (1.f / 64.f);
        }
    }
    // ---- Phase 1b: weight f32 [co][ci][3] -> bf16 wT[tap][co][ci]; zero yT
    // pad rows (p=-1, p=1024) in the first 2048 global threads.
    {
#pragma unroll
        for (int it = 0; it < 8; ++it) {
            int idx = it * (1 << 17) + bid * 512 + t;     // co*1024+ci
            const float* p = w + (size_t)idx * 3;
            wT[idx]             = __float2bfloat16(p[0]);
            wT[(1 << 20) + idx] = __float2bfloat16(p[1]);
            wT[(2 << 20) + idx] = __float2bfloat16(p[2]);
        }
        int g0 = bid * 512 + t;
        if (g0 < 2 * CCH) {
            int bb = g0 >> 10, cc = g0 & 1023;
            __hip_bfloat16 z = __float2bfloat16(0.f);
            __hip_bfloat16* base = yT + (size_t)bb * (PP + 2) * CCH;
            base[cc] = z;
            base[(size_t)(PP + 1) * CCH + cc] = z;
        }
    }
    __threadfence();
    grid.sync();

    // ---- Phase 2: transpose+convert y[b][c][p] -> yT[b][1+p][c] bf16.
    // 8 tiles of 32x32 per block; 512 threads = 32x16, 2 rows each.
    {
        int tx = t & 31, ty = t >> 5;             // 32 x 16
#pragma unroll 1
        for (int i = 0; i < 8; ++i) {
            int tt = bid * 8 + i;                 // 0..2047
            int b = tt >> 10, rem = tt & 1023;
            int c0 = (rem >> 5) * 32, p0 = (rem & 31) * 32;
            const float* yb = y + (size_t)b * CCH * PP;
#pragma unroll
            for (int rr = 0; rr < 2; ++rr)
                lds[(ty + rr * 16) * 33 + tx] = yb[(size_t)(c0 + ty + rr * 16) * PP + p0 + tx];
            __syncthreads();
            __hip_bfloat16* yTb = yT + (size_t)b * (PP + 2) * CCH;
#pragma unroll
            for (int rr = 0; rr < 2; ++rr)
                yTb[(size_t)(1 + p0 + ty + rr * 16) * CCH + c0 + tx] =
                    __float2bfloat16(lds[tx * 33 + ty + rr * 16]);
            __syncthreads();
        }
    }
    __threadfence();
    grid.sync();

    // ---- Phase 3: conv-as-GEMM (64x64 tile, 8 waves of 16x32); 2 jobs/block.
    {
        int wp = wid & 1, wco = wid >> 1;
        int l15 = lane & 15, lhi = lane >> 4;
#pragma unroll 1
        for (int j = 0; j < 2; ++j) {
            int job = bid * 2 + j;                // 0..511
            int bx = job & 15, by = (job >> 4) & 15, bz = job >> 8;
            int co_base = bx * 64 + wco * 16;
            int p_base  = by * 64 + wp * 32;
            const __hip_bfloat16* yTb = yT + (size_t)bz * (PP + 2) * CCH;
            f32x4 acc[2] = {};
#pragma unroll
            for (int tap = 0; tap < 3; ++tap) {
                const __hip_bfloat16* Ap = wT + (size_t)tap * (1u << 20)
                                         + (size_t)(co_base + l15) * CCH + lhi * 8;
                const __hip_bfloat16* Bp = yTb + (size_t)(p_base + l15 + tap) * CCH + lhi * 8;
                for (int ci0 = 0; ci0 < CCH; ci0 += 32) {
                    short8 a0 = *(const short8*)(Ap + ci0);
                    short8 b0 = *(const short8*)(Bp + ci0);
                    short8 b1 = *(const short8*)(Bp + ci0 + 16 * CCH);
                    acc[0] = __builtin_amdgcn_mfma_f32_16x16x32_bf16(a0, b0, acc[0], 0, 0, 0);
                    acc[1] = __builtin_amdgcn_mfma_f32_16x16x32_bf16(a0, b1, acc[1], 0, 0, 0);
                }
            }
            // C/D layout: col = lane&15, row = (lane>>4)*4 + reg  [m89/m91].
            float* gb = gate + (size_t)bz * CCH * PP;
#pragma unroll
            for (int j16 = 0; j16 < 2; ++j16) {
                int col  = p_base + j16 * 16 + l15;
                int row0 = co_base + lhi * 4;
#pragma unroll
                for (int r = 0; r < 4; ++r)
                    gb[(size_t)(row0 + r) * PP + col] = 1.f / (1.f + __expf(-acc[j16][r]));
            }
        }
    }
    __threadfence();
    grid.sync();

    // ---- Phase 4: out = x * gate.  8 planes/block; gate row (4KB) in LDS.
    {
        int col4 = t & 63;
        int r    = t >> 6;                        // 0..7
        int pc   = col4 >> 1;
#pragma unroll 1
        for (int i = 0; i < 8; ++i) {
            int plane = bid * 8 + i;
            const float* xp = x   + (size_t)plane * (HH * WW);
            float*       op = out + (size_t)plane * (HH * WW);
            if (t < 256)
                ((f32x4*)lds)[t] = ((const f32x4*)(gate + (size_t)plane * PP))[t];
            __syncthreads();
#pragma unroll 4
            for (int it = 0; it < 32; ++it) {
                int row = it * 8 + r;
                float gg = lds[(row >> 3) * 32 + pc];
                size_t off = (size_t)row * 64 + col4;    // f32x4 units
                f32x4 v = __builtin_nontemporal_load((const f32x4*)xp + off);
                v *= gg;
                __builtin_nontemporal_store(v, (f32x4*)op + off);
            }
            __syncthreads();
        }
    }
}

// ===========================================================================
// Fallback path: the R5-proven 5-kernel pipeline (used only if the
// cooperative launch is rejected; selection is deterministic per device).
// ===========================================================================
__global__ __launch_bounds__(256) void pool_kernel(const float* __restrict__ x,
                                                   float* __restrict__ y) {
    int bc   = blockIdx.x;
    int wid  = threadIdx.x >> 6;
    int lane = threadIdx.x & 63;
    const float* xp = x + (size_t)bc * (HH * WW) + lane * 4;
    float* yp = y + (size_t)bc * PP;
#pragma unroll
    for (int s = 0; s < 8; ++s) {
        int ph = wid + s * 4;
        const float* slab = xp + (size_t)ph * 8 * WW;
        float acc = 0.f;
#pragma unroll
        for (int r = 0; r < 8; ++r) {
            f32x4 v = __builtin_nontemporal_load((const f32x4*)(slab + (size_t)r * WW));
            acc += v.x + v.y + v.z + v.w;
        }
        acc += __shfl_xor(acc, 1);
        if ((lane & 1) == 0)
            yp[ph * 32 + (lane >> 1)] = acc * (1.f / 64.f);
    }
}

__global__ __launch_bounds__(256) void wconv_pad_kernel(const float* __restrict__ w,
                                                        __hip_bfloat16* __restrict__ wT,
                                                        __hip_bfloat16* __restrict__ yT) {
    int tid = blockIdx.x * 256 + threadIdx.x;
    const float* p = w + (size_t)tid * 3;
    wT[tid]               = __float2bfloat16(p[0]);
    wT[(1u << 20) + tid]  = __float2bfloat16(p[1]);
    wT[(2u << 20) + tid]  = __float2bfloat16(p[2]);
    if (tid < 2 * CCH) {
        int bb = tid >> 10, cc = tid & 1023;
        __hip_bfloat16 z = __float2bfloat16(0.f);
        __hip_bfloat16* base = yT + (size_t)bb * (PP + 2) * CCH;
        base[cc] = z;
        base[(size_t)(PP + 1) * CCH + cc] = z;
    }
}

__global__ __launch_bounds__(256) void transpose_kernel(const float* __restrict__ y,
                                                        __hip_bfloat16* __restrict__ yT) {
    int b  = blockIdx.z;
    int c0 = blockIdx.x * 32;
    int p0 = blockIdx.y * 32;
    __shared__ float tile[32][33];
    int tx = threadIdx.x, ty = threadIdx.y;
    const float* yb = y + (size_t)b * CCH * PP;
#pragma unroll
    for (int rr = 0; rr < 4; ++rr)
        tile[ty + rr * 8][tx] = yb[(size_t)(c0 + ty + rr * 8) * PP + p0 + tx];
    __syncthreads();
    __hip_bfloat16* yTb = yT + (size_t)b * (PP + 2) * CCH;
#pragma unroll
    for (int rr = 0; rr < 4; ++rr)
        yTb[(size_t)(1 + p0 + ty + rr * 8) * CCH + c0 + tx] =
            __float2bfloat16(tile[tx][ty + rr * 8]);
}

__global__ __launch_bounds__(512) void conv_gemm_kernel(
        const __hip_bfloat16* __restrict__ wT,
        const __hip_bfloat16* __restrict__ yT,
        float* __restrict__ gate) {
    int lane = threadIdx.x & 63;
    int wid  = threadIdx.x >> 6;
    int wp  = wid & 1, wco = wid >> 1;
    int l15 = lane & 15, lhi = lane >> 4;
    int co_base = blockIdx.x * 64 + wco * 16;
    int p_base  = blockIdx.y * 64 + wp * 32;
    int b = blockIdx.z;
    const __hip_bfloat16* yTb = yT + (size_t)b * (PP + 2) * CCH;
    f32x4 acc[2] = {};
#pragma unroll
    for (int tap = 0; tap < 3; ++tap) {
        const __hip_bfloat16* Ap = wT + (size_t)tap * (1u << 20)
                                 + (size_t)(co_base + l15) * CCH + lhi * 8;
        const __hip_bfloat16* Bp = yTb + (size_t)(p_base + l15 + tap) * CCH + lhi * 8;
        for (int ci0 = 0; ci0 < CCH; ci0 += 32) {
            short8 a0 = *(const short8*)(Ap + ci0);
            short8 b0 = *(const short8*)(Bp + ci0);
            short8 b1 = *(const short8*)(Bp + ci0 + 16 * CCH);
            acc[0] = __builtin_amdgcn_mfma_f32_16x16x32_bf16(a0, b0, acc[0], 0, 0, 0);
            acc[1] = __builtin_amdgcn_mfma_f32_16x16x32_bf16(a0, b1, acc[1], 0, 0, 0);
        }
    }
    float* gb = gate + (size_t)b * CCH * PP;
#pragma unroll
    for (int j16 = 0; j16 < 2; ++j16) {
        int col  = p_base + j16 * 16 + l15;
        int row0 = co_base + lhi * 4;
#pragma unroll
        for (int r = 0; r < 4; ++r)
            gb[(size_t)(row0 + r) * PP + col] = 1.f / (1.f + __expf(-acc[j16][r]));
    }
}

__global__ __launch_bounds__(256) void apply_kernel(const float* __restrict__ x,
                                                    const float* __restrict__ gate,
                                                    float* __restrict__ out) {
    int bc = blockIdx.x;
    const float* xp = x   + (size_t)bc * (HH * WW);
    float*       op = out + (size_t)bc * (HH * WW);
    __shared__ float g[PP];
    int t = threadIdx.x;
    ((f32x4*)g)[t] = ((const f32x4*)(gate + (size_t)bc * PP))[t];
    __syncthreads();
    int col4 = t & 63;
    int r    = t >> 6;
    int pc   = col4 >> 1;
#pragma unroll 4
    for (int it = 0; it < 64; ++it) {
        int row = it * 4 + r;
        float gg = g[(row >> 3) * 32 + pc];
        size_t off = (size_t)row * 64 + col4;
        f32x4 v = __builtin_nontemporal_load((const f32x4*)xp + off);
        v *= gg;
        __builtin_nontemporal_store(v, (f32x4*)op + off);
    }
}

extern "C" void kernel_launch(void* const* d_in, const int* in_sizes, int n_in,
                              void* d_out, int out_size, void* d_ws, size_t ws_size,
                              hipStream_t stream) {
    const float* x = (const float*)d_in[0];       // [2,1024,256,256] f32
    const float* w = (const float*)d_in[1];       // [1024,1024,3] f32
    float* out = (float*)d_out;                   // [2,1024,256,256] f32

    // Workspace layout (256-aligned):
    //   y    f32  [2][1024][1024]   8,388,608 B @ 0
    //   yT   bf16 [2][1026][1024]   4,202,496 B @  8,388,608
    //   wT   bf16 [3][1024][1024]   6,291,456 B @ 12,591,104
    //   gate f32  [2][1024][1024]   8,388,608 B @ 18,882,560   (tot ~26 MiB)
    char* ws = (char*)d_ws;
    float*          y    = (float*)(ws);
    __hip_bfloat16* yT   = (__hip_bfloat16*)(ws + 8388608);
    __hip_bfloat16* wT   = (__hip_bfloat16*)(ws + 12591104);
    float*          gate = (float*)(ws + 18882560);

    void* args[] = {(void*)&x, (void*)&w, (void*)&out,
                    (void*)&y, (void*)&yT, (void*)&wT, (void*)&gate};
    hipError_t err = hipLaunchCooperativeKernel((const void*)fused_kernel,
                                                dim3(256), dim3(512), args, 0, stream);
    if (err != hipSuccess) {
        (void)hipGetLastError();   // clear sticky error; take the proven path
        hipLaunchKernelGGL(pool_kernel,      dim3(2048),      dim3(256),   0, stream, x, y);
        hipLaunchKernelGGL(wconv_pad_kernel, dim3(4096),      dim3(256),   0, stream, w, wT, yT);
        hipLaunchKernelGGL(transpose_kernel, dim3(32, 32, 2), dim3(32, 8), 0, stream, y, yT);
        hipLaunchKernelGGL(conv_gemm_kernel, dim3(16, 16, 2), dim3(512),   0, stream, wT, yT, gate);
        hipLaunchKernelGGL(apply_kernel,     dim3(2048),      dim3(256),   0, stream, x, gate, out);
    }
}

// Round 8
// 412.781 us; speedup vs baseline: 1.9540x; 1.9540x over previous
//
#include <hip/hip_runtime.h>
#include <hip/hip_bf16.h>

// Problem constants
#define HH 256
#define WW 256
#define CCH 1024
#define PP 1024   // 32*32 patches per image

using f32x4 = __attribute__((ext_vector_type(4))) float;
using short8 = __attribute__((ext_vector_type(8))) short;

// ---------------------------------------------------------------------------
// K_pool (per batch): block per plane c (1024 blocks, 4 waves).  Wave w owns
// patch-rows w, w+4, ..., w+28; reads full 256-col rows (f32x4/lane, CACHED so
// x[b] populates L3 for apply's reversed re-read), shfl_xor(1) pair-reduce,
// even lanes store 32 consecutive f32 (128B line-granular, replay-safe).
// ---------------------------------------------------------------------------
__global__ __launch_bounds__(256) void pool_kernel(const float* __restrict__ xb,
                                                   float* __restrict__ yb) {
    int c    = blockIdx.x;               // plane within batch
    int wid  = threadIdx.x >> 6;
    int lane = threadIdx.x & 63;
    const float* xp = xb + (size_t)c * (HH * WW) + lane * 4;
    float* yp = yb + (size_t)c * PP;
#pragma unroll
    for (int s = 0; s < 8; ++s) {
        int ph = wid + s * 4;
        const float* slab = xp + (size_t)ph * 8 * WW;
        float acc = 0.f;
#pragma unroll
        for (int r = 0; r < 8; ++r) {
            f32x4 v = *(const f32x4*)(slab + (size_t)r * WW);
            acc += v.x + v.y + v.z + v.w;
        }
        acc += __shfl_xor(acc, 1);
        if ((lane & 1) == 0)
            yp[ph * 32 + (lane >> 1)] = acc * (1.f / 64.f);
    }
}

// ---------------------------------------------------------------------------
// K_wconv: f32 [co][ci][3] -> bf16 wT[tap][co][ci]; zero yT pad rows for both
// batches.  Runs FIRST so its w-read doesn't disturb x residency in L3.
// ---------------------------------------------------------------------------
__global__ __launch_bounds__(256) void wconv_pad_kernel(const float* __restrict__ w,
                                                        __hip_bfloat16* __restrict__ wT,
                                                        __hip_bfloat16* __restrict__ yT) {
    int tid = blockIdx.x * 256 + threadIdx.x;
    const float* p = w + (size_t)tid * 3;
    wT[tid]               = __float2bfloat16(p[0]);
    wT[(1u << 20) + tid]  = __float2bfloat16(p[1]);
    wT[(2u << 20) + tid]  = __float2bfloat16(p[2]);
    if (tid < 2 * CCH) {
        int bb = tid >> 10, cc = tid & 1023;
        __hip_bfloat16 z = __float2bfloat16(0.f);
        __hip_bfloat16* base = yT + (size_t)bb * (PP + 2) * CCH;
        base[cc] = z;
        base[(size_t)(PP + 1) * CCH + cc] = z;
    }
}

// ---------------------------------------------------------------------------
// K_transpose (per batch): y[c][p] f32 -> yT[1+p][c] bf16, 32x32 LDS tiles.
// ---------------------------------------------------------------------------
__global__ __launch_bounds__(256) void transpose_kernel(const float* __restrict__ yb,
                                                        __hip_bfloat16* __restrict__ yTb) {
    int c0 = blockIdx.x * 32;
    int p0 = blockIdx.y * 32;
    __shared__ float tile[32][33];
    int tx = threadIdx.x, ty = threadIdx.y;    // 32 x 8
#pragma unroll
    for (int rr = 0; rr < 4; ++rr)
        tile[ty + rr * 8][tx] = yb[(size_t)(c0 + ty + rr * 8) * PP + p0 + tx];
    __syncthreads();
#pragma unroll
    for (int rr = 0; rr < 4; ++rr)
        yTb[(size_t)(1 + p0 + ty + rr * 8) * CCH + c0 + tx] =
            __float2bfloat16(tile[tx][ty + rr * 8]);
}

// ---------------------------------------------------------------------------
// K_gemm (per batch): 64(co) x 64(p) tile, 8 waves of 16x32.  R5-proven body.
// ---------------------------------------------------------------------------
__global__ __launch_bounds__(512) void conv_gemm_kernel(
        const __hip_bfloat16* __restrict__ wT,
        const __hip_bfloat16* __restrict__ yTb,
        float* __restrict__ gateb) {
    int lane = threadIdx.x & 63;
    int wid  = threadIdx.x >> 6;
    int wp  = wid & 1, wco = wid >> 1;
    int l15 = lane & 15, lhi = lane >> 4;
    int co_base = blockIdx.x * 64 + wco * 16;
    int p_base  = blockIdx.y * 64 + wp * 32;
    f32x4 acc[2] = {};
#pragma unroll
    for (int tap = 0; tap < 3; ++tap) {
        const __hip_bfloat16* Ap = wT + (size_t)tap * (1u << 20)
                                 + (size_t)(co_base + l15) * CCH + lhi * 8;
        const __hip_bfloat16* Bp = yTb + (size_t)(p_base + l15 + tap) * CCH + lhi * 8;
        for (int ci0 = 0; ci0 < CCH; ci0 += 32) {
            short8 a0 = *(const short8*)(Ap + ci0);
            short8 b0 = *(const short8*)(Bp + ci0);
            short8 b1 = *(const short8*)(Bp + ci0 + 16 * CCH);
            acc[0] = __builtin_amdgcn_mfma_f32_16x16x32_bf16(a0, b0, acc[0], 0, 0, 0);
            acc[1] = __builtin_amdgcn_mfma_f32_16x16x32_bf16(a0, b1, acc[1], 0, 0, 0);
        }
    }
    // C/D layout: col = lane&15, row = (lane>>4)*4 + reg  [m89/m91].
#pragma unroll
    for (int j16 = 0; j16 < 2; ++j16) {
        int col  = p_base + j16 * 16 + l15;
        int row0 = co_base + lhi * 4;
#pragma unroll
        for (int r = 0; r < 4; ++r)
            gateb[(size_t)(row0 + r) * PP + col] = 1.f / (1.f + __expf(-acc[j16][r]));
    }
}

// ---------------------------------------------------------------------------
// K_apply (per batch, REVERSED): block i processes plane 1023-i, so the planes
// pool read last (L3-resident) are re-read first.  x loads cached (L3 hits);
// out stores non-temporal (no-allocate — don't evict x from L3).
// ---------------------------------------------------------------------------
__global__ __launch_bounds__(256) void apply_kernel(const float* __restrict__ xb,
                                                    const float* __restrict__ gateb,
                                                    float* __restrict__ outb) {
    int c = 1023 - blockIdx.x;           // reversed plane order
    const float* xp = xb   + (size_t)c * (HH * WW);
    float*       op = outb + (size_t)c * (HH * WW);
    __shared__ float g[PP];
    int t = threadIdx.x;
    ((f32x4*)g)[t] = ((const f32x4*)(gateb + (size_t)c * PP))[t];
    __syncthreads();
    int col4 = t & 63;
    int r    = t >> 6;
    int pc   = col4 >> 1;
#pragma unroll 4
    for (int it = 0; it < 64; ++it) {
        int row = it * 4 + r;
        float gg = g[(row >> 3) * 32 + pc];
        size_t off = (size_t)row * 64 + col4;
        f32x4 v = *((const f32x4*)xp + off);
        v *= gg;
        __builtin_nontemporal_store(v, (f32x4*)op + off);
    }
}

extern "C" void kernel_launch(void* const* d_in, const int* in_sizes, int n_in,
                              void* d_out, int out_size, void* d_ws, size_t ws_size,
                              hipStream_t stream) {
    const float* x = (const float*)d_in[0];       // [2,1024,256,256] f32
    const float* w = (const float*)d_in[1];       // [1024,1024,3] f32
    float* out = (float*)d_out;                   // [2,1024,256,256] f32

    // Workspace layout (256-aligned):
    //   y    f32  [2][1024][1024]   8,388,608 B @ 0
    //   yT   bf16 [2][1026][1024]   4,202,496 B @  8,388,608
    //   wT   bf16 [3][1024][1024]   6,291,456 B @ 12,591,104
    //   gate f32  [2][1024][1024]   8,388,608 B @ 18,882,560   (tot ~26 MiB)
    char* ws = (char*)d_ws;
    float*          y    = (float*)(ws);
    __hip_bfloat16* yT   = (__hip_bfloat16*)(ws + 8388608);
    __hip_bfloat16* wT   = (__hip_bfloat16*)(ws + 12591104);
    float*          gate = (float*)(ws + 18882560);

    hipLaunchKernelGGL(wconv_pad_kernel, dim3(4096), dim3(256), 0, stream, w, wT, yT);
    for (int b = 0; b < 2; ++b) {
        const float* xb = x + (size_t)b * CCH * HH * WW;
        float* yb       = y + (size_t)b * CCH * PP;
        __hip_bfloat16* yTb = yT + (size_t)b * (PP + 2) * CCH;
        float* gateb    = gate + (size_t)b * CCH * PP;
        float* outb     = out + (size_t)b * CCH * HH * WW;
        hipLaunchKernelGGL(pool_kernel,      dim3(1024),      dim3(256),   0, stream, xb, yb);
        hipLaunchKernelGGL(transpose_kernel, dim3(32, 32),    dim3(32, 8), 0, stream, yb, yTb);
        hipLaunchKernelGGL(conv_gemm_kernel, dim3(16, 16),    dim3(512),   0, stream, wT, yTb, gateb);
        hipLaunchKernelGGL(apply_kernel,     dim3(1024),      dim3(256),   0, stream, xb, gateb, outb);
    }
}